// Round 2
// baseline (297.682 us; speedup 1.0000x reference)
//
#include <hip/hip_runtime.h>
#include <hip/hip_bf16.h>

typedef unsigned int uint;
typedef unsigned short ushort;
typedef __attribute__((ext_vector_type(4))) float f32x4;
typedef __attribute__((ext_vector_type(8))) __bf16 bf16x8;
typedef __attribute__((ext_vector_type(8))) ushort ushort8;

#define MFMA16(a, b, c) __builtin_amdgcn_mfma_f32_16x16x32_bf16((a), (b), (c), 0, 0, 0)

__device__ __forceinline__ ushort f2bf(float x) {
    uint u = __float_as_uint(x);
    u += 0x7fff + ((u >> 16) & 1);   // RNE
    return (ushort)(u >> 16);
}
__device__ __forceinline__ float bf2f(ushort h) {
    return __uint_as_float((uint)h << 16);
}

__device__ __forceinline__ void gload_lds16(const void* g, void* l) {
    __builtin_amdgcn_global_load_lds(
        (const __attribute__((address_space(1))) void*)g,
        (__attribute__((address_space(3))) void*)l, 16, 0, 0);
}

// ------- fp32 -> (hi, lo) bf16 split, 8 elems/thread -------
__global__ __launch_bounds__(256) void cvt_split(const float* __restrict__ src,
                                                 ushort* __restrict__ hi,
                                                 ushort* __restrict__ lo, int n8) {
    int i = blockIdx.x * blockDim.x + threadIdx.x;
    if (i >= n8) return;
    const float4* s4 = reinterpret_cast<const float4*>(src);
    float4 a = s4[2 * i], b = s4[2 * i + 1];
    float v[8] = {a.x, a.y, a.z, a.w, b.x, b.y, b.z, b.w};
    ushort8 oh, ol;
#pragma unroll
    for (int j = 0; j < 8; ++j) {
        ushort h = f2bf(v[j]);
        oh[j] = h;
        ol[j] = f2bf(v[j] - bf2f(h));
    }
    *reinterpret_cast<ushort8*>(hi + i * 8) = oh;
    *reinterpret_cast<ushort8*>(lo + i * 8) = ol;
}

// ---------------- fused QKV projection GEMM (split-precision for Q,K) ----------------
// z=0: Q = xW^T (3 passes hi/lo), split-output; z=1: K likewise; z=2: V single pass.
// out bf16 [ (b*16+h) ][ s ][ d ], m=b*2048+s, n=h*64+d
__global__ __launch_bounds__(256) void qkv_gemm(const ushort* __restrict__ xh,
                                                const ushort* __restrict__ xl,
                                                const ushort* __restrict__ wh,
                                                const ushort* __restrict__ wl,
                                                const float* __restrict__ bq,
                                                const float* __restrict__ bk,
                                                const float* __restrict__ bv,
                                                ushort* __restrict__ qh, ushort* __restrict__ ql,
                                                ushort* __restrict__ kh, ushort* __restrict__ kl,
                                                ushort* __restrict__ vv) {
    __shared__ ushort As[128 * 64];
    __shared__ ushort Bs[128 * 64];
    const int tid = threadIdx.x;
    const int l = tid & 63, w = tid >> 6;
    const int lrow = l & 15, lhi = l >> 4;
    const int wr = w >> 1, wc = w & 1;
    const int m0 = blockIdx.x * 128;
    const int n0 = blockIdx.y * 128;
    const int z = blockIdx.z;
    const ushort* whz = wh + z * (1024 * 1024);
    const ushort* wlz = wl + z * (1024 * 1024);
    const float* bias = (z == 0) ? bq : (z == 1) ? bk : bv;
    ushort* dsthi = (z == 0) ? qh : (z == 1) ? kh : vv;
    ushort* dstlo = (z == 0) ? ql : kl;   // unused for z==2

    f32x4 acc[4][4] = {};
    const int srow = w * 32 + (l >> 3);               // +i*8
    const int scol = ((l & 7) ^ (l >> 3)) * 8;        // pre-swizzled k-col (rule #21)
    const int lds0 = w * 2048;                        // +i*512
    const int arow = wr * 64 + lrow;
    const int brow = wc * 64 + lrow;

    const int npass = (z == 2) ? 1 : 3;
    for (int pass = 0; pass < npass; ++pass) {
        const ushort* Ag = (pass == 2) ? xl : xh;
        const ushort* Bg = (pass == 1) ? wlz : whz;
        for (int kt = 0; kt < 16; ++kt) {
            const int kb = kt * 64;
#pragma unroll
            for (int i = 0; i < 4; ++i)
                gload_lds16(Ag + (m0 + srow + i * 8) * 1024 + kb + scol, &As[lds0 + i * 512]);
#pragma unroll
            for (int i = 0; i < 4; ++i)
                gload_lds16(Bg + (n0 + srow + i * 8) * 1024 + kb + scol, &Bs[lds0 + i * 512]);
            __syncthreads();
#pragma unroll
            for (int kk = 0; kk < 2; ++kk) {
                const int csw = ((kk * 4 + lhi) ^ (lrow & 7)) * 8;
                bf16x8 af[4], bfr[4];
#pragma unroll
                for (int mi = 0; mi < 4; ++mi)
                    af[mi] = *reinterpret_cast<const bf16x8*>(&As[(arow + mi * 16) * 64 + csw]);
#pragma unroll
                for (int ni = 0; ni < 4; ++ni)
                    bfr[ni] = *reinterpret_cast<const bf16x8*>(&Bs[(brow + ni * 16) * 64 + csw]);
#pragma unroll
                for (int mi = 0; mi < 4; ++mi)
#pragma unroll
                    for (int ni = 0; ni < 4; ++ni)
                        acc[mi][ni] = MFMA16(af[mi], bfr[ni], acc[mi][ni]);
            }
            __syncthreads();
        }
    }
    // epilogue: bias add, hi/lo split, scatter to [bh][s][d]
    float bcol[4];
#pragma unroll
    for (int ni = 0; ni < 4; ++ni) bcol[ni] = bias[n0 + wc * 64 + ni * 16 + lrow];
#pragma unroll
    for (int mi = 0; mi < 4; ++mi) {
#pragma unroll
        for (int r = 0; r < 4; ++r) {
            const int m = m0 + wr * 64 + mi * 16 + lhi * 4 + r;
            const int bb = m >> 11, s = m & 2047;
#pragma unroll
            for (int ni = 0; ni < 4; ++ni) {
                const int n = n0 + wc * 64 + ni * 16 + lrow;
                const int h = n >> 6, d = n & 63;
                const int idx = ((bb * 16 + h) * 2048 + s) * 64 + d;
                float val = acc[mi][ni][r] + bcol[ni];
                ushort hbits = f2bf(val);
                dsthi[idx] = hbits;
                if (z < 2) dstlo[idx] = f2bf(val - bf2f(hbits));
            }
        }
    }
}

// ---------------- flash attention (no scale), split-precision QK^T ----------------
__global__ __launch_bounds__(256) void attn_fwd(const ushort* __restrict__ Qhg,
                                                const ushort* __restrict__ Qlg,
                                                const ushort* __restrict__ Khg,
                                                const ushort* __restrict__ Klg,
                                                const ushort* __restrict__ Vg,
                                                float* __restrict__ out) {
    __shared__ ushort Qsh[64][72];
    __shared__ ushort Qsl[64][72];
    __shared__ ushort Ksh[64][72];
    __shared__ ushort Ksl[64][72];
    __shared__ ushort Vt[64][72];     // V transposed: [d][kv]
    __shared__ ushort Ps[4][16][72];  // per-wave P tile
    const int tid = threadIdx.x;
    const int l = tid & 63, w = tid >> 6;
    const int lrow = l & 15, lhi = l >> 4;
    const int qt = blockIdx.x, bh = blockIdx.y;
    const int b = bh >> 4, h = bh & 15;
    const int qoff = (bh * 2048 + qt * 64) * 64;
    const int kvoff = bh * 2048 * 64;

    // stage Q (hi+lo) once
#pragma unroll
    for (int p = 0; p < 2; ++p) {
        int idx = p * 256 + tid;
        int row = idx >> 3, c8 = (idx & 7) * 8;
        *reinterpret_cast<uint4*>(&Qsh[row][c8]) =
            *reinterpret_cast<const uint4*>(Qhg + qoff + row * 64 + c8);
        *reinterpret_cast<uint4*>(&Qsl[row][c8]) =
            *reinterpret_cast<const uint4*>(Qlg + qoff + row * 64 + c8);
    }

    float m_run[4], l_run[4];
    f32x4 o[4];
#pragma unroll
    for (int r = 0; r < 4; ++r) { m_run[r] = -1e30f; l_run[r] = 0.f; }
#pragma unroll
    for (int ni = 0; ni < 4; ++ni) o[ni] = f32x4{0.f, 0.f, 0.f, 0.f};

    for (int t = 0; t < 32; ++t) {
        __syncthreads();  // previous tile's LDS reads done (also fences Q stage)
        // stage K hi/lo
#pragma unroll
        for (int p = 0; p < 2; ++p) {
            int idx = p * 256 + tid;
            int row = idx >> 3, c8 = (idx & 7) * 8;
            *reinterpret_cast<uint4*>(&Ksh[row][c8]) =
                *reinterpret_cast<const uint4*>(Khg + kvoff + (t * 64 + row) * 64 + c8);
            *reinterpret_cast<uint4*>(&Ksl[row][c8]) =
                *reinterpret_cast<const uint4*>(Klg + kvoff + (t * 64 + row) * 64 + c8);
        }
        // stage V transposed
#pragma unroll
        for (int p = 0; p < 2; ++p) {
            int idx = p * 256 + tid;
            int kv = idx >> 3, d0 = (idx & 7) * 8;
            uint4 v = *reinterpret_cast<const uint4*>(Vg + kvoff + (t * 64 + kv) * 64 + d0);
            const ushort* pv = reinterpret_cast<const ushort*>(&v);
#pragma unroll
            for (int j = 0; j < 8; ++j) Vt[d0 + j][kv] = pv[j];
        }
        __syncthreads();

        // S = Qhi Khi^T + Qhi Klo^T + Qlo Khi^T for this wave's 16 q-rows x 64 kv
        f32x4 sc[4];
#pragma unroll
        for (int ni = 0; ni < 4; ++ni) sc[ni] = f32x4{0.f, 0.f, 0.f, 0.f};
#pragma unroll
        for (int pass = 0; pass < 3; ++pass) {
            const ushort(*Qsrc)[72] = (pass == 2) ? Qsl : Qsh;
            const ushort(*Ksrc)[72] = (pass == 1) ? Ksl : Ksh;
#pragma unroll
            for (int kk = 0; kk < 2; ++kk) {
                bf16x8 aq = *reinterpret_cast<const bf16x8*>(&Qsrc[w * 16 + lrow][kk * 32 + lhi * 8]);
#pragma unroll
                for (int ni = 0; ni < 4; ++ni) {
                    bf16x8 bk8 = *reinterpret_cast<const bf16x8*>(&Ksrc[ni * 16 + lrow][kk * 32 + lhi * 8]);
                    sc[ni] = MFMA16(aq, bk8, sc[ni]);
                }
            }
        }
        // online softmax (rows: q = w*16 + lhi*4 + r; cols: kv = ni*16 + lrow)
#pragma unroll
        for (int r = 0; r < 4; ++r) {
            float mx = fmaxf(fmaxf(sc[0][r], sc[1][r]), fmaxf(sc[2][r], sc[3][r]));
#pragma unroll
            for (int msk = 1; msk < 16; msk <<= 1) mx = fmaxf(mx, __shfl_xor(mx, msk, 64));
            float mnew = fmaxf(m_run[r], mx);
            float alpha = __expf(m_run[r] - mnew);
            float lsum = 0.f;
            ushort pb[4];
#pragma unroll
            for (int ni = 0; ni < 4; ++ni) {
                float pvf = __expf(sc[ni][r] - mnew);
                pb[ni] = f2bf(pvf);
                lsum += bf2f(pb[ni]);  // rounded p for consistent normalization
            }
#pragma unroll
            for (int msk = 1; msk < 16; msk <<= 1) lsum += __shfl_xor(lsum, msk, 64);
            l_run[r] = l_run[r] * alpha + lsum;
            m_run[r] = mnew;
#pragma unroll
            for (int ni = 0; ni < 4; ++ni) o[ni][r] *= alpha;
#pragma unroll
            for (int ni = 0; ni < 4; ++ni) Ps[w][lhi * 4 + r][ni * 16 + lrow] = pb[ni];
        }
        __syncthreads();  // fence P writes
        // O += P V
#pragma unroll
        for (int kk = 0; kk < 2; ++kk) {
            bf16x8 ap = *reinterpret_cast<const bf16x8*>(&Ps[w][lrow][kk * 32 + lhi * 8]);
#pragma unroll
            for (int ni = 0; ni < 4; ++ni) {
                bf16x8 bv8 = *reinterpret_cast<const bf16x8*>(&Vt[ni * 16 + lrow][kk * 32 + lhi * 8]);
                o[ni] = MFMA16(ap, bv8, o[ni]);
            }
        }
    }
    // epilogue: normalize and store fp32 [b][s][h*64+d]
#pragma unroll
    for (int ni = 0; ni < 4; ++ni) {
#pragma unroll
        for (int r = 0; r < 4; ++r) {
            int q = qt * 64 + w * 16 + lhi * 4 + r;
            int d = ni * 16 + lrow;
            out[(b * 2048 + q) * 1024 + h * 64 + d] = o[ni][r] / l_run[r];
        }
    }
}

extern "C" void kernel_launch(void* const* d_in, const int* in_sizes, int n_in,
                              void* d_out, int out_size, void* d_ws, size_t ws_size,
                              hipStream_t stream) {
    const float* x  = (const float*)d_in[0];
    const float* Wq = (const float*)d_in[1];
    const float* bq = (const float*)d_in[2];
    const float* Wk = (const float*)d_in[3];
    const float* bk = (const float*)d_in[4];
    const float* Wv = (const float*)d_in[5];
    const float* bv = (const float*)d_in[6];
    float* outp = (float*)d_out;

    ushort* ws = (ushort*)d_ws;
    const size_t XM = 4096 * 1024;   // 4.19M elems
    const size_t WM = 1024 * 1024;
    ushort* xh = ws;                  // x hi
    ushort* xl = xh + XM;             // x lo
    ushort* wh = xl + XM;             // Wq,Wk,Wv hi (3 x WM)
    ushort* wl = wh + 3 * WM;         // Wq,Wk,Wv lo (3 x WM; Wv lo unused)
    ushort* qh = wl + 3 * WM;         // Q hi  [32][2048][64]
    ushort* ql = qh + XM;             // Q lo
    ushort* kh = ql + XM;             // K hi
    ushort* kl = kh + XM;             // K lo
    ushort* vv = kl + XM;             // V

    cvt_split<<<2048, 256, 0, stream>>>(x, xh, xl, (int)(XM / 8));
    cvt_split<<<512, 256, 0, stream>>>(Wq, wh, wl, (int)(WM / 8));
    cvt_split<<<512, 256, 0, stream>>>(Wk, wh + WM, wl + WM, (int)(WM / 8));
    cvt_split<<<512, 256, 0, stream>>>(Wv, wh + 2 * WM, wl + 2 * WM, (int)(WM / 8));

    qkv_gemm<<<dim3(32, 8, 3), 256, 0, stream>>>(xh, xl, wh, wl, bq, bk, bv,
                                                 qh, ql, kh, kl, vv);

    attn_fwd<<<dim3(32, 32), 256, 0, stream>>>(qh, ql, kh, kl, vv, outp);
}

// Round 3
// 221.936 us; speedup vs baseline: 1.3413x; 1.3413x over previous
//
#include <hip/hip_runtime.h>
#include <hip/hip_bf16.h>

typedef unsigned int uint;
typedef unsigned short ushort;
typedef __attribute__((ext_vector_type(4))) float f32x4;
typedef __attribute__((ext_vector_type(8))) __bf16 bf16x8;
typedef __attribute__((ext_vector_type(8))) ushort ushort8;

#define MFMA16(a, b, c) __builtin_amdgcn_mfma_f32_16x16x32_bf16((a), (b), (c), 0, 0, 0)

__device__ __forceinline__ ushort f2bf(float x) {
    uint u = __float_as_uint(x);
    u += 0x7fff + ((u >> 16) & 1);   // RNE
    return (ushort)(u >> 16);
}
__device__ __forceinline__ float bf2f(ushort h) {
    return __uint_as_float((uint)h << 16);
}

__device__ __forceinline__ void gload_lds16(const void* g, void* l) {
    __builtin_amdgcn_global_load_lds(
        (const __attribute__((address_space(1))) void*)g,
        (__attribute__((address_space(3))) void*)l, 16, 0, 0);
}

// ------- fp32 -> (hi, lo) bf16 split, 8 elems/thread -------
__global__ __launch_bounds__(256) void cvt_split(const float* __restrict__ src,
                                                 ushort* __restrict__ hi,
                                                 ushort* __restrict__ lo, int n8) {
    int i = blockIdx.x * blockDim.x + threadIdx.x;
    if (i >= n8) return;
    const float4* s4 = reinterpret_cast<const float4*>(src);
    float4 a = s4[2 * i], b = s4[2 * i + 1];
    float v[8] = {a.x, a.y, a.z, a.w, b.x, b.y, b.z, b.w};
    ushort8 oh, ol;
#pragma unroll
    for (int j = 0; j < 8; ++j) {
        ushort h = f2bf(v[j]);
        oh[j] = h;
        ol[j] = f2bf(v[j] - bf2f(h));
    }
    *reinterpret_cast<ushort8*>(hi + i * 8) = oh;
    *reinterpret_cast<ushort8*>(lo + i * 8) = ol;
}

// ---------------- fused QKV projection GEMM (split-precision for Q,K) ----------------
__global__ __launch_bounds__(256) void qkv_gemm(const ushort* __restrict__ xh,
                                                const ushort* __restrict__ xl,
                                                const ushort* __restrict__ wh,
                                                const ushort* __restrict__ wl,
                                                const float* __restrict__ bq,
                                                const float* __restrict__ bk,
                                                const float* __restrict__ bv,
                                                ushort* __restrict__ qh, ushort* __restrict__ ql,
                                                ushort* __restrict__ kh, ushort* __restrict__ kl,
                                                ushort* __restrict__ vv) {
    __shared__ ushort As[128 * 64];
    __shared__ ushort Bs[128 * 64];
    const int tid = threadIdx.x;
    const int l = tid & 63, w = tid >> 6;
    const int lrow = l & 15, lhi = l >> 4;
    const int wr = w >> 1, wc = w & 1;
    const int m0 = blockIdx.x * 128;
    const int n0 = blockIdx.y * 128;
    const int z = blockIdx.z;
    const ushort* whz = wh + z * (1024 * 1024);
    const ushort* wlz = wl + z * (1024 * 1024);
    const float* bias = (z == 0) ? bq : (z == 1) ? bk : bv;
    ushort* dsthi = (z == 0) ? qh : (z == 1) ? kh : vv;
    ushort* dstlo = (z == 0) ? ql : kl;   // unused for z==2

    f32x4 acc[4][4] = {};
    const int srow = w * 32 + (l >> 3);               // +i*8
    const int scol = ((l & 7) ^ (l >> 3)) * 8;        // pre-swizzled k-col (rule #21)
    const int lds0 = w * 2048;                        // +i*512
    const int arow = wr * 64 + lrow;
    const int brow = wc * 64 + lrow;

    const int npass = (z == 2) ? 1 : 3;
    for (int pass = 0; pass < npass; ++pass) {
        const ushort* Ag = (pass == 2) ? xl : xh;
        const ushort* Bg = (pass == 1) ? wlz : whz;
        for (int kt = 0; kt < 16; ++kt) {
            const int kb = kt * 64;
#pragma unroll
            for (int i = 0; i < 4; ++i)
                gload_lds16(Ag + (m0 + srow + i * 8) * 1024 + kb + scol, &As[lds0 + i * 512]);
#pragma unroll
            for (int i = 0; i < 4; ++i)
                gload_lds16(Bg + (n0 + srow + i * 8) * 1024 + kb + scol, &Bs[lds0 + i * 512]);
            __syncthreads();
#pragma unroll
            for (int kk = 0; kk < 2; ++kk) {
                const int csw = ((kk * 4 + lhi) ^ (lrow & 7)) * 8;
                bf16x8 af[4], bfr[4];
#pragma unroll
                for (int mi = 0; mi < 4; ++mi)
                    af[mi] = *reinterpret_cast<const bf16x8*>(&As[(arow + mi * 16) * 64 + csw]);
#pragma unroll
                for (int ni = 0; ni < 4; ++ni)
                    bfr[ni] = *reinterpret_cast<const bf16x8*>(&Bs[(brow + ni * 16) * 64 + csw]);
#pragma unroll
                for (int mi = 0; mi < 4; ++mi)
#pragma unroll
                    for (int ni = 0; ni < 4; ++ni)
                        acc[mi][ni] = MFMA16(af[mi], bfr[ni], acc[mi][ni]);
            }
            __syncthreads();
        }
    }
    float bcol[4];
#pragma unroll
    for (int ni = 0; ni < 4; ++ni) bcol[ni] = bias[n0 + wc * 64 + ni * 16 + lrow];
#pragma unroll
    for (int mi = 0; mi < 4; ++mi) {
#pragma unroll
        for (int r = 0; r < 4; ++r) {
            const int m = m0 + wr * 64 + mi * 16 + lhi * 4 + r;
            const int bb = m >> 11, s = m & 2047;
#pragma unroll
            for (int ni = 0; ni < 4; ++ni) {
                const int n = n0 + wc * 64 + ni * 16 + lrow;
                const int h = n >> 6, d = n & 63;
                const int idx = ((bb * 16 + h) * 2048 + s) * 64 + d;
                float val = acc[mi][ni][r] + bcol[ni];
                ushort hbits = f2bf(val);
                dsthi[idx] = hbits;
                if (z < 2) dstlo[idx] = f2bf(val - bf2f(hbits));
            }
        }
    }
}

// ------- V [bh][s][d] -> Vt [bh][d][s] (one-time transpose) -------
__global__ __launch_bounds__(256) void transpose_v(const ushort* __restrict__ Vg,
                                                   ushort* __restrict__ Vt) {
    __shared__ ushort buf[64 * 68];   // pitch 68: 8B-aligned writes, 4-way-max col reads
    const int tid = threadIdx.x;
    const int st = blockIdx.x, bh = blockIdx.y;
    const ushort* src = Vg + ((size_t)bh * 2048 + st * 64) * 64;
#pragma unroll
    for (int p = 0; p < 2; ++p) {
        int idx = p * 256 + tid;
        int row = idx >> 3, c8 = (idx & 7) * 8;
        uint4 v = *reinterpret_cast<const uint4*>(src + row * 64 + c8);
        *reinterpret_cast<uint2*>(&buf[row * 68 + c8]) = make_uint2(v.x, v.y);
        *reinterpret_cast<uint2*>(&buf[row * 68 + c8 + 4]) = make_uint2(v.z, v.w);
    }
    __syncthreads();
    const int l = tid & 63, w = tid >> 6;
    ushort* dst = Vt + (size_t)bh * 64 * 2048 + st * 64;
#pragma unroll
    for (int i = 0; i < 16; ++i) {
        int d = i * 4 + w;
        dst[d * 2048 + l] = buf[l * 68 + d];
    }
}

// ---------------- flash attention: Q in regs, gload_lds staging, pre-transposed V ----------------
__global__ __launch_bounds__(256, 4) void attn_fwd(const ushort* __restrict__ Qhg,
                                                   const ushort* __restrict__ Qlg,
                                                   const ushort* __restrict__ Khg,
                                                   const ushort* __restrict__ Klg,
                                                   const ushort* __restrict__ Vtg,
                                                   float* __restrict__ out) {
    __shared__ ushort Ksh[64 * 64];
    __shared__ ushort Ksl[64 * 64];
    __shared__ ushort Vts[64 * 64];
    __shared__ ushort Ps[4][16][72];
    const int tid = threadIdx.x;
    const int l = tid & 63, w = tid >> 6;
    const int lrow = l & 15, lhi = l >> 4;
    const int qt = blockIdx.x, bh = blockIdx.y;
    const int b = bh >> 4, h = bh & 15;
    const size_t qoff = ((size_t)bh * 2048 + qt * 64) * 64;
    const size_t kvoff = (size_t)bh * 2048 * 64;
    const size_t vtoff = (size_t)bh * 64 * 2048;

    // Q hi/lo A-fragments hoisted to registers (wave-constant across KV tiles)
    bf16x8 aqh[2], aql[2];
#pragma unroll
    for (int kk = 0; kk < 2; ++kk) {
        const size_t qa = qoff + (w * 16 + lrow) * 64 + kk * 32 + lhi * 8;
        aqh[kk] = *reinterpret_cast<const bf16x8*>(Qhg + qa);
        aql[kk] = *reinterpret_cast<const bf16x8*>(Qlg + qa);
    }

    const int srow = w * 16 + (l >> 3);           // + i*8
    const int scol = ((l & 7) ^ (l >> 3)) * 8;    // pre-swizzled source col (rule #21)
    const int lds0 = w * 1024;                    // + i*512

    float m_run[4], l_run[4];
    f32x4 o[4];
#pragma unroll
    for (int r = 0; r < 4; ++r) { m_run[r] = -1e30f; l_run[r] = 0.f; }
#pragma unroll
    for (int ni = 0; ni < 4; ++ni) o[ni] = f32x4{0.f, 0.f, 0.f, 0.f};

    for (int t = 0; t < 32; ++t) {
        __syncthreads();  // prior tile's LDS reads complete before overwrite
#pragma unroll
        for (int i = 0; i < 2; ++i) {
            const size_t gk = kvoff + (size_t)(t * 64 + srow + i * 8) * 64 + scol;
            const size_t gv = vtoff + (size_t)(srow + i * 8) * 2048 + t * 64 + scol;
            gload_lds16(Khg + gk, &Ksh[lds0 + i * 512]);
            gload_lds16(Klg + gk, &Ksl[lds0 + i * 512]);
            gload_lds16(Vtg + gv, &Vts[lds0 + i * 512]);
        }
        __syncthreads();  // compiler drains vmcnt before barrier

        // S = Qh·Kh + Qh·Kl + Ql·Kh  (each K-frag loaded once)
        f32x4 sc[4];
#pragma unroll
        for (int ni = 0; ni < 4; ++ni) sc[ni] = f32x4{0.f, 0.f, 0.f, 0.f};
#pragma unroll
        for (int kk = 0; kk < 2; ++kk) {
#pragma unroll
            for (int ni = 0; ni < 4; ++ni) {
                const int off = (ni * 16 + lrow) * 64 + (((kk * 4 + lhi) ^ (lrow & 7)) * 8);
                bf16x8 khf = *reinterpret_cast<const bf16x8*>(&Ksh[off]);
                bf16x8 klf = *reinterpret_cast<const bf16x8*>(&Ksl[off]);
                sc[ni] = MFMA16(aqh[kk], khf, sc[ni]);
                sc[ni] = MFMA16(aqh[kk], klf, sc[ni]);
                sc[ni] = MFMA16(aql[kk], khf, sc[ni]);
            }
        }
        // online softmax (rows: q = w*16 + lhi*4 + r; cols: kv = ni*16 + lrow)
#pragma unroll
        for (int r = 0; r < 4; ++r) {
            float mx = fmaxf(fmaxf(sc[0][r], sc[1][r]), fmaxf(sc[2][r], sc[3][r]));
#pragma unroll
            for (int msk = 1; msk < 16; msk <<= 1) mx = fmaxf(mx, __shfl_xor(mx, msk, 64));
            float mnew = fmaxf(m_run[r], mx);
            float alpha = __expf(m_run[r] - mnew);
            float lsum = 0.f;
            ushort pb[4];
#pragma unroll
            for (int ni = 0; ni < 4; ++ni) {
                float pvf = __expf(sc[ni][r] - mnew);
                pb[ni] = f2bf(pvf);
                lsum += bf2f(pb[ni]);
            }
#pragma unroll
            for (int msk = 1; msk < 16; msk <<= 1) lsum += __shfl_xor(lsum, msk, 64);
            l_run[r] = l_run[r] * alpha + lsum;
            m_run[r] = mnew;
#pragma unroll
            for (int ni = 0; ni < 4; ++ni) o[ni][r] *= alpha;
#pragma unroll
            for (int ni = 0; ni < 4; ++ni) Ps[w][lhi * 4 + r][ni * 16 + lrow] = pb[ni];
        }
        __syncthreads();  // fence P writes
        // O += P · V  (B-frag = Vt[d][kv], same swizzled pattern)
#pragma unroll
        for (int kk = 0; kk < 2; ++kk) {
            bf16x8 ap = *reinterpret_cast<const bf16x8*>(&Ps[w][lrow][kk * 32 + lhi * 8]);
#pragma unroll
            for (int ni = 0; ni < 4; ++ni) {
                const int off = (ni * 16 + lrow) * 64 + (((kk * 4 + lhi) ^ (lrow & 7)) * 8);
                bf16x8 bv8 = *reinterpret_cast<const bf16x8*>(&Vts[off]);
                o[ni] = MFMA16(ap, bv8, o[ni]);
            }
        }
    }
    // epilogue: normalize and store fp32 [b][s][h*64+d]
#pragma unroll
    for (int ni = 0; ni < 4; ++ni) {
#pragma unroll
        for (int r = 0; r < 4; ++r) {
            int q = qt * 64 + w * 16 + lhi * 4 + r;
            int d = ni * 16 + lrow;
            out[((size_t)b * 2048 + q) * 1024 + h * 64 + d] = o[ni][r] / l_run[r];
        }
    }
}

extern "C" void kernel_launch(void* const* d_in, const int* in_sizes, int n_in,
                              void* d_out, int out_size, void* d_ws, size_t ws_size,
                              hipStream_t stream) {
    const float* x  = (const float*)d_in[0];
    const float* Wq = (const float*)d_in[1];
    const float* bq = (const float*)d_in[2];
    const float* Wk = (const float*)d_in[3];
    const float* bk = (const float*)d_in[4];
    const float* Wv = (const float*)d_in[5];
    const float* bv = (const float*)d_in[6];
    float* outp = (float*)d_out;

    ushort* ws = (ushort*)d_ws;
    const size_t XM = 4096 * 1024;
    const size_t WM = 1024 * 1024;
    ushort* xh = ws;                  // x hi       [0, XM)      -- dead after qkv_gemm
    ushort* xl = xh + XM;             // x lo
    ushort* wh = xl + XM;             // W hi (3 x WM)
    ushort* wl = wh + 3 * WM;         // W lo (3 x WM)
    ushort* qh = wl + 3 * WM;         // Q hi  [32][2048][64]
    ushort* ql = qh + XM;             // Q lo
    ushort* kh = ql + XM;             // K hi
    ushort* kl = kh + XM;             // K lo
    ushort* vv = kl + XM;             // V   [bh][s][d]
    ushort* vt = xh;                  // V^T [bh][d][s] -- aliases xh (safe: stream-ordered)

    cvt_split<<<2048, 256, 0, stream>>>(x, xh, xl, (int)(XM / 8));
    cvt_split<<<512, 256, 0, stream>>>(Wq, wh, wl, (int)(WM / 8));
    cvt_split<<<512, 256, 0, stream>>>(Wk, wh + WM, wl + WM, (int)(WM / 8));
    cvt_split<<<512, 256, 0, stream>>>(Wv, wh + 2 * WM, wl + 2 * WM, (int)(WM / 8));

    qkv_gemm<<<dim3(32, 8, 3), 256, 0, stream>>>(xh, xl, wh, wl, bq, bk, bv,
                                                 qh, ql, kh, kl, vv);

    transpose_v<<<dim3(32, 32), 256, 0, stream>>>(vv, vt);

    attn_fwd<<<dim3(32, 32), 256, 0, stream>>>(qh, ql, kh, kl, vt, outp);
}

// Round 4
// 204.156 us; speedup vs baseline: 1.4581x; 1.0871x over previous
//
#include <hip/hip_runtime.h>
#include <hip/hip_bf16.h>

typedef unsigned int uint;
typedef unsigned short ushort;
typedef __attribute__((ext_vector_type(4))) float f32x4;
typedef __attribute__((ext_vector_type(8))) __bf16 bf16x8;
typedef __attribute__((ext_vector_type(8))) ushort ushort8;

#define MFMA16(a, b, c) __builtin_amdgcn_mfma_f32_16x16x32_bf16((a), (b), (c), 0, 0, 0)

__device__ __forceinline__ ushort f2bf(float x) {
    uint u = __float_as_uint(x);
    u += 0x7fff + ((u >> 16) & 1);   // RNE
    return (ushort)(u >> 16);
}
__device__ __forceinline__ float bf2f(ushort h) {
    return __uint_as_float((uint)h << 16);
}

__device__ __forceinline__ void gload_lds16(const void* g, void* l) {
    __builtin_amdgcn_global_load_lds(
        (const __attribute__((address_space(1))) void*)g,
        (__attribute__((address_space(3))) void*)l, 16, 0, 0);
}

// DPP row-rotate (within 16-lane rows) — VALU-pipe cross-lane, ~4cy vs ds_swizzle ~35cy
template <int CTRL>
__device__ __forceinline__ float dppf(float x) {
    return __int_as_float(__builtin_amdgcn_update_dpp(
        __float_as_int(x), __float_as_int(x), CTRL, 0xF, 0xF, false));
}
__device__ __forceinline__ float rowmax16(float x) {
    x = fmaxf(x, dppf<0x121>(x));   // row_ror:1
    x = fmaxf(x, dppf<0x122>(x));   // row_ror:2
    x = fmaxf(x, dppf<0x124>(x));   // row_ror:4
    x = fmaxf(x, dppf<0x128>(x));   // row_ror:8
    return x;
}
__device__ __forceinline__ float rowsum16(float x) {
    x += dppf<0x121>(x);
    x += dppf<0x122>(x);
    x += dppf<0x124>(x);
    x += dppf<0x128>(x);
    return x;
}

// ------- fp32 -> (hi, lo) bf16 split, 8 elems/thread -------
__global__ __launch_bounds__(256) void cvt_split(const float* __restrict__ src,
                                                 ushort* __restrict__ hi,
                                                 ushort* __restrict__ lo, int n8) {
    int i = blockIdx.x * blockDim.x + threadIdx.x;
    if (i >= n8) return;
    const float4* s4 = reinterpret_cast<const float4*>(src);
    float4 a = s4[2 * i], b = s4[2 * i + 1];
    float v[8] = {a.x, a.y, a.z, a.w, b.x, b.y, b.z, b.w};
    ushort8 oh, ol;
#pragma unroll
    for (int j = 0; j < 8; ++j) {
        ushort h = f2bf(v[j]);
        oh[j] = h;
        ol[j] = f2bf(v[j] - bf2f(h));
    }
    *reinterpret_cast<ushort8*>(hi + i * 8) = oh;
    *reinterpret_cast<ushort8*>(lo + i * 8) = ol;
}

// ---------------- fused QKV projection GEMM (split-precision for Q,K) ----------------
// All 3 correction terms (xh·Wh + xh·Wl + xl·Wh) fused per K-step: 96 MFMA/barrier-pair.
__global__ __launch_bounds__(256, 2) void qkv_gemm(const ushort* __restrict__ xh,
                                                   const ushort* __restrict__ xl,
                                                   const ushort* __restrict__ wh,
                                                   const ushort* __restrict__ wl,
                                                   const float* __restrict__ bq,
                                                   const float* __restrict__ bk,
                                                   const float* __restrict__ bv,
                                                   ushort* __restrict__ qh, ushort* __restrict__ ql,
                                                   ushort* __restrict__ kh, ushort* __restrict__ kl,
                                                   ushort* __restrict__ vv) {
    __shared__ ushort Ash[128 * 64];
    __shared__ ushort Asl[128 * 64];
    __shared__ ushort Bsh[128 * 64];
    __shared__ ushort Bsl[128 * 64];
    const int tid = threadIdx.x;
    const int l = tid & 63, w = tid >> 6;
    const int lrow = l & 15, lhi = l >> 4;
    const int wr = w >> 1, wc = w & 1;
    const int m0 = blockIdx.x * 128;
    const int n0 = blockIdx.y * 128;
    const int z = blockIdx.z;
    const ushort* whz = wh + z * (1024 * 1024);
    const ushort* wlz = wl + z * (1024 * 1024);
    const float* bias = (z == 0) ? bq : (z == 1) ? bk : bv;
    ushort* dsthi = (z == 0) ? qh : (z == 1) ? kh : vv;
    ushort* dstlo = (z == 0) ? ql : kl;   // unused for z==2

    f32x4 acc[4][4] = {};
    const int srow = w * 32 + (l >> 3);               // +i*8
    const int scol = ((l & 7) ^ (l >> 3)) * 8;        // pre-swizzled k-col (rule #21)
    const int lds0 = w * 2048;                        // +i*512
    const int arow = wr * 64 + lrow;
    const int brow = wc * 64 + lrow;

    for (int kt = 0; kt < 16; ++kt) {
        const int kb = kt * 64;
#pragma unroll
        for (int i = 0; i < 4; ++i) {
            gload_lds16(xh + (m0 + srow + i * 8) * 1024 + kb + scol, &Ash[lds0 + i * 512]);
            gload_lds16(whz + (n0 + srow + i * 8) * 1024 + kb + scol, &Bsh[lds0 + i * 512]);
        }
        if (z < 2) {
#pragma unroll
            for (int i = 0; i < 4; ++i) {
                gload_lds16(xl + (m0 + srow + i * 8) * 1024 + kb + scol, &Asl[lds0 + i * 512]);
                gload_lds16(wlz + (n0 + srow + i * 8) * 1024 + kb + scol, &Bsl[lds0 + i * 512]);
            }
        }
        __syncthreads();
#pragma unroll
        for (int kk = 0; kk < 2; ++kk) {
            const int csw = ((kk * 4 + lhi) ^ (lrow & 7)) * 8;
            bf16x8 afh[4], afl[4];
#pragma unroll
            for (int mi = 0; mi < 4; ++mi)
                afh[mi] = *reinterpret_cast<const bf16x8*>(&Ash[(arow + mi * 16) * 64 + csw]);
            if (z < 2) {
#pragma unroll
                for (int mi = 0; mi < 4; ++mi)
                    afl[mi] = *reinterpret_cast<const bf16x8*>(&Asl[(arow + mi * 16) * 64 + csw]);
            }
            __builtin_amdgcn_s_setprio(1);
#pragma unroll
            for (int ni = 0; ni < 4; ++ni) {
                bf16x8 bh8 = *reinterpret_cast<const bf16x8*>(&Bsh[(brow + ni * 16) * 64 + csw]);
#pragma unroll
                for (int mi = 0; mi < 4; ++mi)
                    acc[mi][ni] = MFMA16(afh[mi], bh8, acc[mi][ni]);
                if (z < 2) {
                    bf16x8 bl8 = *reinterpret_cast<const bf16x8*>(&Bsl[(brow + ni * 16) * 64 + csw]);
#pragma unroll
                    for (int mi = 0; mi < 4; ++mi)
                        acc[mi][ni] = MFMA16(afh[mi], bl8, acc[mi][ni]);
#pragma unroll
                    for (int mi = 0; mi < 4; ++mi)
                        acc[mi][ni] = MFMA16(afl[mi], bh8, acc[mi][ni]);
                }
            }
            __builtin_amdgcn_s_setprio(0);
        }
        __syncthreads();
    }
    float bcol[4];
#pragma unroll
    for (int ni = 0; ni < 4; ++ni) bcol[ni] = bias[n0 + wc * 64 + ni * 16 + lrow];
#pragma unroll
    for (int mi = 0; mi < 4; ++mi) {
#pragma unroll
        for (int r = 0; r < 4; ++r) {
            const int m = m0 + wr * 64 + mi * 16 + lhi * 4 + r;
            const int bb = m >> 11, s = m & 2047;
#pragma unroll
            for (int ni = 0; ni < 4; ++ni) {
                const int n = n0 + wc * 64 + ni * 16 + lrow;
                const int h = n >> 6, d = n & 63;
                const int idx = ((bb * 16 + h) * 2048 + s) * 64 + d;
                float val = acc[mi][ni][r] + bcol[ni];
                ushort hbits = f2bf(val);
                dsthi[idx] = hbits;
                if (z < 2) dstlo[idx] = f2bf(val - bf2f(hbits));
            }
        }
    }
}

// ------- V [bh][s][d] -> Vt [bh][d][s] (one-time transpose) -------
__global__ __launch_bounds__(256) void transpose_v(const ushort* __restrict__ Vg,
                                                   ushort* __restrict__ Vt) {
    __shared__ ushort buf[64 * 68];
    const int tid = threadIdx.x;
    const int st = blockIdx.x, bh = blockIdx.y;
    const ushort* src = Vg + ((size_t)bh * 2048 + st * 64) * 64;
#pragma unroll
    for (int p = 0; p < 2; ++p) {
        int idx = p * 256 + tid;
        int row = idx >> 3, c8 = (idx & 7) * 8;
        uint4 v = *reinterpret_cast<const uint4*>(src + row * 64 + c8);
        *reinterpret_cast<uint2*>(&buf[row * 68 + c8]) = make_uint2(v.x, v.y);
        *reinterpret_cast<uint2*>(&buf[row * 68 + c8 + 4]) = make_uint2(v.z, v.w);
    }
    __syncthreads();
    const int l = tid & 63, w = tid >> 6;
    ushort* dst = Vt + (size_t)bh * 64 * 2048 + st * 64;
#pragma unroll
    for (int i = 0; i < 16; ++i) {
        int d = i * 4 + w;
        dst[d * 2048 + l] = buf[l * 68 + d];
    }
}

// ---------------- flash attention: dbuf prefetch, 1 barrier/tile, DPP softmax ----------------
__global__ __launch_bounds__(256, 2) void attn_fwd(const ushort* __restrict__ Qhg,
                                                   const ushort* __restrict__ Qlg,
                                                   const ushort* __restrict__ Khg,
                                                   const ushort* __restrict__ Klg,
                                                   const ushort* __restrict__ Vtg,
                                                   float* __restrict__ out) {
    __shared__ ushort Ksh[2][64 * 64];
    __shared__ ushort Ksl[2][64 * 64];
    __shared__ ushort Vts[2][64 * 64];
    __shared__ ushort Ps[4][16][72];
    const int tid = threadIdx.x;
    const int l = tid & 63, w = tid >> 6;
    const int lrow = l & 15, lhi = l >> 4;
    const int qt = blockIdx.x, bh = blockIdx.y;
    const int b = bh >> 4, h = bh & 15;
    const size_t qoff = ((size_t)bh * 2048 + qt * 64) * 64;
    const size_t kvoff = (size_t)bh * 2048 * 64;
    const size_t vtoff = (size_t)bh * 64 * 2048;

    // Q hi/lo A-fragments in registers (wave-constant across KV tiles)
    bf16x8 aqh[2], aql[2];
#pragma unroll
    for (int kk = 0; kk < 2; ++kk) {
        const size_t qa = qoff + (w * 16 + lrow) * 64 + kk * 32 + lhi * 8;
        aqh[kk] = *reinterpret_cast<const bf16x8*>(Qhg + qa);
        aql[kk] = *reinterpret_cast<const bf16x8*>(Qlg + qa);
    }

    const int srow = w * 16 + (l >> 3);           // + i*8
    const int scol = ((l & 7) ^ (l >> 3)) * 8;    // pre-swizzled source col (rule #21)
    const int lds0 = w * 1024;                    // + i*512

    float m_run[4], l_run[4];
    f32x4 o[4];
#pragma unroll
    for (int r = 0; r < 4; ++r) { m_run[r] = -1e30f; l_run[r] = 0.f; }
#pragma unroll
    for (int ni = 0; ni < 4; ++ni) o[ni] = f32x4{0.f, 0.f, 0.f, 0.f};

    auto stage = [&](int buf, int t) {
#pragma unroll
        for (int i = 0; i < 2; ++i) {
            const size_t gk = kvoff + (size_t)(t * 64 + srow + i * 8) * 64 + scol;
            const size_t gv = vtoff + (size_t)(srow + i * 8) * 2048 + t * 64 + scol;
            gload_lds16(Khg + gk, &Ksh[buf][lds0 + i * 512]);
            gload_lds16(Klg + gk, &Ksl[buf][lds0 + i * 512]);
            gload_lds16(Vtg + gv, &Vts[buf][lds0 + i * 512]);
        }
    };

    auto tilecomp = [&](int buf) {
        // S = Qh·Kh + Qh·Kl + Ql·Kh
        f32x4 sc[4];
#pragma unroll
        for (int ni = 0; ni < 4; ++ni) sc[ni] = f32x4{0.f, 0.f, 0.f, 0.f};
        __builtin_amdgcn_s_setprio(1);
#pragma unroll
        for (int kk = 0; kk < 2; ++kk) {
#pragma unroll
            for (int ni = 0; ni < 4; ++ni) {
                const int off = (ni * 16 + lrow) * 64 + (((kk * 4 + lhi) ^ (lrow & 7)) * 8);
                bf16x8 khf = *reinterpret_cast<const bf16x8*>(&Ksh[buf][off]);
                bf16x8 klf = *reinterpret_cast<const bf16x8*>(&Ksl[buf][off]);
                sc[ni] = MFMA16(aqh[kk], khf, sc[ni]);
                sc[ni] = MFMA16(aqh[kk], klf, sc[ni]);
                sc[ni] = MFMA16(aql[kk], khf, sc[ni]);
            }
        }
        __builtin_amdgcn_s_setprio(0);
        // row maxes via DPP (rows: q = w*16 + lhi*4 + r; cols: kv = ni*16 + lrow)
        float mxr[4];
#pragma unroll
        for (int r = 0; r < 4; ++r) {
            float m3 = fmaxf(fmaxf(sc[0][r], sc[1][r]), fmaxf(sc[2][r], sc[3][r]));
            mxr[r] = rowmax16(m3);
        }
        bool grow = (mxr[0] > m_run[0] + 8.f) || (mxr[1] > m_run[1] + 8.f) ||
                    (mxr[2] > m_run[2] + 8.f) || (mxr[3] > m_run[3] + 8.f);
        if (__any(grow)) {
#pragma unroll
            for (int r = 0; r < 4; ++r) {
                float mnew = fmaxf(m_run[r], mxr[r]);
                float alpha = __expf(m_run[r] - mnew);
                float lsum = 0.f;
#pragma unroll
                for (int ni = 0; ni < 4; ++ni) {
                    float pvf = __expf(sc[ni][r] - mnew);
                    lsum += pvf;
                    Ps[w][lhi * 4 + r][ni * 16 + lrow] = f2bf(pvf);
                }
                lsum = rowsum16(lsum);
                l_run[r] = l_run[r] * alpha + lsum;
                m_run[r] = mnew;
#pragma unroll
                for (int ni = 0; ni < 4; ++ni) o[ni][r] *= alpha;
            }
        } else {  // defer-max fast path (THR=8): no rescale, keep old max
#pragma unroll
            for (int r = 0; r < 4; ++r) {
                float lsum = 0.f;
#pragma unroll
                for (int ni = 0; ni < 4; ++ni) {
                    float pvf = __expf(sc[ni][r] - m_run[r]);
                    lsum += pvf;
                    Ps[w][lhi * 4 + r][ni * 16 + lrow] = f2bf(pvf);
                }
                lsum = rowsum16(lsum);
                l_run[r] += lsum;
            }
        }
        // O += P · V  (wave-private Ps: compiler lgkmcnt orders write->read, no barrier)
        __builtin_amdgcn_s_setprio(1);
#pragma unroll
        for (int kk = 0; kk < 2; ++kk) {
            bf16x8 ap = *reinterpret_cast<const bf16x8*>(&Ps[w][lrow][kk * 32 + lhi * 8]);
#pragma unroll
            for (int ni = 0; ni < 4; ++ni) {
                const int off = (ni * 16 + lrow) * 64 + (((kk * 4 + lhi) ^ (lrow & 7)) * 8);
                bf16x8 bv8 = *reinterpret_cast<const bf16x8*>(&Vts[buf][off]);
                o[ni] = MFMA16(ap, bv8, o[ni]);
            }
        }
        __builtin_amdgcn_s_setprio(0);
    };

    stage(0, 0);
    __syncthreads();
#pragma unroll 1
    for (int tt = 0; tt < 16; ++tt) {
        stage(1, tt * 2 + 1);          // prefetch odd tile while computing even
        tilecomp(0);
        __syncthreads();               // buf1 ready; everyone done reading buf0
        if (tt < 15) stage(0, tt * 2 + 2);
        tilecomp(1);
        __syncthreads();
    }

    // epilogue: normalize and store fp32 [b][s][h*64+d]
#pragma unroll
    for (int ni = 0; ni < 4; ++ni) {
#pragma unroll
        for (int r = 0; r < 4; ++r) {
            int q = qt * 64 + w * 16 + lhi * 4 + r;
            int d = ni * 16 + lrow;
            out[((size_t)b * 2048 + q) * 1024 + h * 64 + d] = o[ni][r] / l_run[r];
        }
    }
}

extern "C" void kernel_launch(void* const* d_in, const int* in_sizes, int n_in,
                              void* d_out, int out_size, void* d_ws, size_t ws_size,
                              hipStream_t stream) {
    const float* x  = (const float*)d_in[0];
    const float* Wq = (const float*)d_in[1];
    const float* bq = (const float*)d_in[2];
    const float* Wk = (const float*)d_in[3];
    const float* bk = (const float*)d_in[4];
    const float* Wv = (const float*)d_in[5];
    const float* bv = (const float*)d_in[6];
    float* outp = (float*)d_out;

    ushort* ws = (ushort*)d_ws;
    const size_t XM = 4096 * 1024;
    const size_t WM = 1024 * 1024;
    ushort* xh = ws;                  // x hi -- dead after qkv_gemm
    ushort* xl = xh + XM;
    ushort* wh = xl + XM;             // W hi (3 x WM)
    ushort* wl = wh + 3 * WM;         // W lo (3 x WM)
    ushort* qh = wl + 3 * WM;         // Q hi  [32][2048][64]
    ushort* ql = qh + XM;             // Q lo
    ushort* kh = ql + XM;             // K hi
    ushort* kl = kh + XM;             // K lo
    ushort* vv = kl + XM;             // V   [bh][s][d]
    ushort* vt = xh;                  // V^T [bh][d][s] -- aliases xh (stream-ordered)

    cvt_split<<<2048, 256, 0, stream>>>(x, xh, xl, (int)(XM / 8));
    cvt_split<<<512, 256, 0, stream>>>(Wq, wh, wl, (int)(WM / 8));
    cvt_split<<<512, 256, 0, stream>>>(Wk, wh + WM, wl + WM, (int)(WM / 8));
    cvt_split<<<512, 256, 0, stream>>>(Wv, wh + 2 * WM, wl + 2 * WM, (int)(WM / 8));

    qkv_gemm<<<dim3(32, 8, 3), 256, 0, stream>>>(xh, xl, wh, wl, bq, bk, bv,
                                                 qh, ql, kh, kl, vv);

    transpose_v<<<dim3(32, 32), 256, 0, stream>>>(vv, vt);

    attn_fwd<<<dim3(32, 32), 256, 0, stream>>>(qh, ql, kh, kl, vt, outp);
}

// Round 5
// 193.217 us; speedup vs baseline: 1.5407x; 1.0566x over previous
//
#include <hip/hip_runtime.h>
#include <hip/hip_bf16.h>

typedef unsigned int uint;
typedef unsigned short ushort;
typedef __attribute__((ext_vector_type(4))) float f32x4;
typedef __attribute__((ext_vector_type(8))) __bf16 bf16x8;
typedef __attribute__((ext_vector_type(8))) ushort ushort8;

#define MFMA16(a, b, c) __builtin_amdgcn_mfma_f32_16x16x32_bf16((a), (b), (c), 0, 0, 0)

__device__ __forceinline__ ushort f2bf(float x) {
    uint u = __float_as_uint(x);
    u += 0x7fff + ((u >> 16) & 1);   // RNE
    return (ushort)(u >> 16);
}
__device__ __forceinline__ float bf2f(ushort h) {
    return __uint_as_float((uint)h << 16);
}
// pack two f32 -> u32 of 2 bf16 (lo in [15:0]) — T12 recipe, RNE
__device__ __forceinline__ uint cvtpk_bf16(float lo, float hi) {
    uint r;
    asm("v_cvt_pk_bf16_f32 %0, %1, %2" : "=v"(r) : "v"(lo), "v"(hi));
    return r;
}

__device__ __forceinline__ void gload_lds16(const void* g, void* l) {
    __builtin_amdgcn_global_load_lds(
        (const __attribute__((address_space(1))) void*)g,
        (__attribute__((address_space(3))) void*)l, 16, 0, 0);
}

// ------- fp32 -> (hi, lo) bf16 split, 8 elems/thread -------
__global__ __launch_bounds__(256) void cvt_split(const float* __restrict__ src,
                                                 ushort* __restrict__ hi,
                                                 ushort* __restrict__ lo, int n8) {
    int i = blockIdx.x * blockDim.x + threadIdx.x;
    if (i >= n8) return;
    const float4* s4 = reinterpret_cast<const float4*>(src);
    float4 a = s4[2 * i], b = s4[2 * i + 1];
    float v[8] = {a.x, a.y, a.z, a.w, b.x, b.y, b.z, b.w};
    ushort8 oh, ol;
#pragma unroll
    for (int j = 0; j < 8; ++j) {
        ushort h = f2bf(v[j]);
        oh[j] = h;
        ol[j] = f2bf(v[j] - bf2f(h));
    }
    *reinterpret_cast<ushort8*>(hi + i * 8) = oh;
    *reinterpret_cast<ushort8*>(lo + i * 8) = ol;
}

// ---------------- fused QKV projection GEMM (split-precision for Q,K) ----------------
__global__ __launch_bounds__(256, 2) void qkv_gemm(const ushort* __restrict__ xh,
                                                   const ushort* __restrict__ xl,
                                                   const ushort* __restrict__ wh,
                                                   const ushort* __restrict__ wl,
                                                   const float* __restrict__ bq,
                                                   const float* __restrict__ bk,
                                                   const float* __restrict__ bv,
                                                   ushort* __restrict__ qh, ushort* __restrict__ ql,
                                                   ushort* __restrict__ kh, ushort* __restrict__ kl,
                                                   ushort* __restrict__ vv) {
    __shared__ ushort Ash[128 * 64];
    __shared__ ushort Asl[128 * 64];
    __shared__ ushort Bsh[128 * 64];
    __shared__ ushort Bsl[128 * 64];
    const int tid = threadIdx.x;
    const int l = tid & 63, w = tid >> 6;
    const int lrow = l & 15, lhi = l >> 4;
    const int wr = w >> 1, wc = w & 1;
    const int m0 = blockIdx.x * 128;
    const int n0 = blockIdx.y * 128;
    const int z = blockIdx.z;
    const ushort* whz = wh + z * (1024 * 1024);
    const ushort* wlz = wl + z * (1024 * 1024);
    const float* bias = (z == 0) ? bq : (z == 1) ? bk : bv;
    ushort* dsthi = (z == 0) ? qh : (z == 1) ? kh : vv;
    ushort* dstlo = (z == 0) ? ql : kl;   // unused for z==2

    f32x4 acc[4][4] = {};
    const int srow = w * 32 + (l >> 3);               // +i*8
    const int scol = ((l & 7) ^ (l >> 3)) * 8;        // pre-swizzled k-col (rule #21)
    const int lds0 = w * 2048;                        // +i*512
    const int arow = wr * 64 + lrow;
    const int brow = wc * 64 + lrow;

    for (int kt = 0; kt < 16; ++kt) {
        const int kb = kt * 64;
#pragma unroll
        for (int i = 0; i < 4; ++i) {
            gload_lds16(xh + (m0 + srow + i * 8) * 1024 + kb + scol, &Ash[lds0 + i * 512]);
            gload_lds16(whz + (n0 + srow + i * 8) * 1024 + kb + scol, &Bsh[lds0 + i * 512]);
        }
        if (z < 2) {
#pragma unroll
            for (int i = 0; i < 4; ++i) {
                gload_lds16(xl + (m0 + srow + i * 8) * 1024 + kb + scol, &Asl[lds0 + i * 512]);
                gload_lds16(wlz + (n0 + srow + i * 8) * 1024 + kb + scol, &Bsl[lds0 + i * 512]);
            }
        }
        __syncthreads();
#pragma unroll
        for (int kk = 0; kk < 2; ++kk) {
            const int csw = ((kk * 4 + lhi) ^ (lrow & 7)) * 8;
            bf16x8 afh[4], afl[4];
#pragma unroll
            for (int mi = 0; mi < 4; ++mi)
                afh[mi] = *reinterpret_cast<const bf16x8*>(&Ash[(arow + mi * 16) * 64 + csw]);
            if (z < 2) {
#pragma unroll
                for (int mi = 0; mi < 4; ++mi)
                    afl[mi] = *reinterpret_cast<const bf16x8*>(&Asl[(arow + mi * 16) * 64 + csw]);
            }
            __builtin_amdgcn_s_setprio(1);
#pragma unroll
            for (int ni = 0; ni < 4; ++ni) {
                bf16x8 bh8 = *reinterpret_cast<const bf16x8*>(&Bsh[(brow + ni * 16) * 64 + csw]);
#pragma unroll
                for (int mi = 0; mi < 4; ++mi)
                    acc[mi][ni] = MFMA16(afh[mi], bh8, acc[mi][ni]);
                if (z < 2) {
                    bf16x8 bl8 = *reinterpret_cast<const bf16x8*>(&Bsl[(brow + ni * 16) * 64 + csw]);
#pragma unroll
                    for (int mi = 0; mi < 4; ++mi)
                        acc[mi][ni] = MFMA16(afh[mi], bl8, acc[mi][ni]);
#pragma unroll
                    for (int mi = 0; mi < 4; ++mi)
                        acc[mi][ni] = MFMA16(afl[mi], bh8, acc[mi][ni]);
                }
            }
            __builtin_amdgcn_s_setprio(0);
        }
        __syncthreads();
    }
    float bcol[4];
#pragma unroll
    for (int ni = 0; ni < 4; ++ni) bcol[ni] = bias[n0 + wc * 64 + ni * 16 + lrow];
#pragma unroll
    for (int mi = 0; mi < 4; ++mi) {
#pragma unroll
        for (int r = 0; r < 4; ++r) {
            const int m = m0 + wr * 64 + mi * 16 + lhi * 4 + r;
            const int bb = m >> 11, s = m & 2047;
#pragma unroll
            for (int ni = 0; ni < 4; ++ni) {
                const int n = n0 + wc * 64 + ni * 16 + lrow;
                const int h = n >> 6, d = n & 63;
                const int idx = ((bb * 16 + h) * 2048 + s) * 64 + d;
                float val = acc[mi][ni][r] + bcol[ni];
                ushort hbits = f2bf(val);
                dsthi[idx] = hbits;
                if (z < 2) dstlo[idx] = f2bf(val - bf2f(hbits));
            }
        }
    }
}

// ------- V [bh][s][d] -> Vt [bh][d][s] (one-time transpose) -------
__global__ __launch_bounds__(256) void transpose_v(const ushort* __restrict__ Vg,
                                                   ushort* __restrict__ Vt) {
    __shared__ ushort buf[64 * 68];
    const int tid = threadIdx.x;
    const int st = blockIdx.x, bh = blockIdx.y;
    const ushort* src = Vg + ((size_t)bh * 2048 + st * 64) * 64;
#pragma unroll
    for (int p = 0; p < 2; ++p) {
        int idx = p * 256 + tid;
        int row = idx >> 3, c8 = (idx & 7) * 8;
        uint4 v = *reinterpret_cast<const uint4*>(src + row * 64 + c8);
        *reinterpret_cast<uint2*>(&buf[row * 68 + c8]) = make_uint2(v.x, v.y);
        *reinterpret_cast<uint2*>(&buf[row * 68 + c8 + 4]) = make_uint2(v.z, v.w);
    }
    __syncthreads();
    const int l = tid & 63, w = tid >> 6;
    ushort* dst = Vt + (size_t)bh * 64 * 2048 + st * 64;
#pragma unroll
    for (int i = 0; i < 16; ++i) {
        int d = i * 4 + w;
        dst[d * 2048 + l] = buf[l * 68 + d];
    }
}

// ---- flash attention: swapped QK^T, in-register P redistribution, no Ps LDS ----
__global__ __launch_bounds__(256, 3) void attn_fwd(const ushort* __restrict__ Qhg,
                                                   const ushort* __restrict__ Qlg,
                                                   const ushort* __restrict__ Khg,
                                                   const ushort* __restrict__ Klg,
                                                   const ushort* __restrict__ Vtg,
                                                   float* __restrict__ out) {
    __shared__ ushort Ksh[2][64 * 64];
    __shared__ ushort Ksl[2][64 * 64];
    __shared__ ushort Vts[2][64 * 64];
    const int tid = threadIdx.x;
    const int l = tid & 63, w = tid >> 6;
    const int lrow = l & 15, lhi = l >> 4;
    const int qt = blockIdx.x, bh = blockIdx.y;
    const int b = bh >> 4, h = bh & 15;
    const size_t qoff = ((size_t)bh * 2048 + qt * 64) * 64;
    const size_t kvoff = (size_t)bh * 2048 * 64;
    const size_t vtoff = (size_t)bh * 64 * 2048;

    // Q hi/lo fragments (serve as MFMA B-operand after the QK swap — same bits)
    bf16x8 aqh[2], aql[2];
#pragma unroll
    for (int kk = 0; kk < 2; ++kk) {
        const size_t qa = qoff + (w * 16 + lrow) * 64 + kk * 32 + lhi * 8;
        aqh[kk] = *reinterpret_cast<const bf16x8*>(Qhg + qa);
        aql[kk] = *reinterpret_cast<const bf16x8*>(Qlg + qa);
    }

    const int srow = w * 16 + (l >> 3);           // + i*8
    const int scol = ((l & 7) ^ (l >> 3)) * 8;    // pre-swizzled source col (rule #21)
    const int lds0 = w * 1024;                    // + i*512

    // P-redistribution lane constants (derived mapping, see analysis):
    //   c=0 src lane = lrow + 32*(lhi&1); c=1 src = +16; register = pk[2kk + (lhi>>1)]
    const int s0 = lrow + 32 * (lhi & 1);
    const int s1 = s0 + 16;
    const bool abit = (lhi >> 1) != 0;
    const int bl = (lhi << 4) + lhi * 4;          // broadcast lane base: + r

    float m_run = -1e30f, l_run = 0.f;            // per-thread scalars (q = w*16+lrow)
    f32x4 o[4];
#pragma unroll
    for (int ni = 0; ni < 4; ++ni) o[ni] = f32x4{0.f, 0.f, 0.f, 0.f};

    auto stage = [&](int buf, int t) {
#pragma unroll
        for (int i = 0; i < 2; ++i) {
            const size_t gk = kvoff + (size_t)(t * 64 + srow + i * 8) * 64 + scol;
            const size_t gv = vtoff + (size_t)(srow + i * 8) * 2048 + t * 64 + scol;
            gload_lds16(Khg + gk, &Ksh[buf][lds0 + i * 512]);
            gload_lds16(Klg + gk, &Ksl[buf][lds0 + i * 512]);
            gload_lds16(Vtg + gv, &Vts[buf][lds0 + i * 512]);
        }
    };

    auto tilecomp = [&](int buf) {
        // S^T tiles: sc[ni] = K_tile(ni) x Q  -> thread holds full q-row:
        //   q = w*16 + lrow,  kv = ni*16 + lhi*4 + r
        f32x4 sc[4];
#pragma unroll
        for (int ni = 0; ni < 4; ++ni) sc[ni] = f32x4{0.f, 0.f, 0.f, 0.f};
        __builtin_amdgcn_s_setprio(1);
#pragma unroll
        for (int kk = 0; kk < 2; ++kk) {
#pragma unroll
            for (int ni = 0; ni < 4; ++ni) {
                const int off = (ni * 16 + lrow) * 64 + (((kk * 4 + lhi) ^ (lrow & 7)) * 8);
                bf16x8 khf = *reinterpret_cast<const bf16x8*>(&Ksh[buf][off]);
                bf16x8 klf = *reinterpret_cast<const bf16x8*>(&Ksl[buf][off]);
                sc[ni] = MFMA16(khf, aqh[kk], sc[ni]);   // swapped operands
                sc[ni] = MFMA16(klf, aqh[kk], sc[ni]);
                sc[ni] = MFMA16(khf, aql[kk], sc[ni]);
            }
        }
        __builtin_amdgcn_s_setprio(0);

        // row max: thread-local over 16, then across the 4 lanes sharing this q-row
        float mx = fmaxf(fmaxf(sc[0][0], sc[0][1]), fmaxf(sc[0][2], sc[0][3]));
#pragma unroll
        for (int ni = 1; ni < 4; ++ni)
            mx = fmaxf(mx, fmaxf(fmaxf(sc[ni][0], sc[ni][1]), fmaxf(sc[ni][2], sc[ni][3])));
        mx = fmaxf(mx, __shfl_xor(mx, 16, 64));
        mx = fmaxf(mx, __shfl_xor(mx, 32, 64));

        bool rescale = false;
        float alpha = 1.f;
        if (__any(mx > m_run + 8.f)) {            // defer-max THR=8 (wave-uniform)
            float mnew = fmaxf(m_run, mx);
            alpha = __expf(m_run - mnew);
            m_run = mnew;
            rescale = true;
        }
        // exp + pack to bf16 pairs
        float p[4][4];
        float lsum = 0.f;
#pragma unroll
        for (int ni = 0; ni < 4; ++ni)
#pragma unroll
            for (int r = 0; r < 4; ++r) {
                p[ni][r] = __expf(sc[ni][r] - m_run);
                lsum += p[ni][r];
            }
        uint pk[4][2];
#pragma unroll
        for (int ni = 0; ni < 4; ++ni) {
            pk[ni][0] = cvtpk_bf16(p[ni][0], p[ni][1]);
            pk[ni][1] = cvtpk_bf16(p[ni][2], p[ni][3]);
        }
        lsum += __shfl_xor(lsum, 16, 64);
        lsum += __shfl_xor(lsum, 32, 64);
        if (rescale) {
            l_run = l_run * alpha + lsum;
            float ao0 = __shfl(alpha, bl + 0, 64);
            float ao1 = __shfl(alpha, bl + 1, 64);
            float ao2 = __shfl(alpha, bl + 2, 64);
            float ao3 = __shfl(alpha, bl + 3, 64);
#pragma unroll
            for (int ni = 0; ni < 4; ++ni) {
                o[ni][0] *= ao0; o[ni][1] *= ao1; o[ni][2] *= ao2; o[ni][3] *= ao3;
            }
        } else {
            l_run += lsum;
        }
        // redistribute P into PV A-fragments (16 shfl + 8 select)
        uint apw[2][4];
#pragma unroll
        for (int kk = 0; kk < 2; ++kk) {
            int t0, t1;
            t0 = __shfl((int)pk[2 * kk][0], s0, 64); t1 = __shfl((int)pk[2 * kk + 1][0], s0, 64);
            apw[kk][0] = (uint)(abit ? t1 : t0);
            t0 = __shfl((int)pk[2 * kk][1], s0, 64); t1 = __shfl((int)pk[2 * kk + 1][1], s0, 64);
            apw[kk][1] = (uint)(abit ? t1 : t0);
            t0 = __shfl((int)pk[2 * kk][0], s1, 64); t1 = __shfl((int)pk[2 * kk + 1][0], s1, 64);
            apw[kk][2] = (uint)(abit ? t1 : t0);
            t0 = __shfl((int)pk[2 * kk][1], s1, 64); t1 = __shfl((int)pk[2 * kk + 1][1], s1, 64);
            apw[kk][3] = (uint)(abit ? t1 : t0);
        }
        // O += P · V
        __builtin_amdgcn_s_setprio(1);
#pragma unroll
        for (int kk = 0; kk < 2; ++kk) {
            bf16x8 ap = *reinterpret_cast<const bf16x8*>(&apw[kk][0]);
#pragma unroll
            for (int ni = 0; ni < 4; ++ni) {
                const int off = (ni * 16 + lrow) * 64 + (((kk * 4 + lhi) ^ (lrow & 7)) * 8);
                bf16x8 bv8 = *reinterpret_cast<const bf16x8*>(&Vts[buf][off]);
                o[ni] = MFMA16(ap, bv8, o[ni]);
            }
        }
        __builtin_amdgcn_s_setprio(0);
    };

    stage(0, 0);
    __syncthreads();
#pragma unroll 1
    for (int tt = 0; tt < 16; ++tt) {
        stage(1, tt * 2 + 1);          // prefetch odd tile while computing even
        tilecomp(0);
        __syncthreads();               // buf1 ready; everyone done reading buf0
        if (tt < 15) stage(0, tt * 2 + 2);
        tilecomp(1);
        __syncthreads();
    }

    // epilogue: normalize (l for q-row lhi*4+r fetched from its tracking lane)
    float ln0 = __shfl(l_run, bl + 0, 64);
    float ln1 = __shfl(l_run, bl + 1, 64);
    float ln2 = __shfl(l_run, bl + 2, 64);
    float ln3 = __shfl(l_run, bl + 3, 64);
#pragma unroll
    for (int ni = 0; ni < 4; ++ni) {
        const int q = qt * 64 + w * 16 + lhi * 4;
        const int d = ni * 16 + lrow;
        float* op = out + ((size_t)b * 2048 + q) * 1024 + h * 64 + d;
        op[0]        = o[ni][0] / ln0;
        op[1024]     = o[ni][1] / ln1;
        op[2 * 1024] = o[ni][2] / ln2;
        op[3 * 1024] = o[ni][3] / ln3;
    }
}

extern "C" void kernel_launch(void* const* d_in, const int* in_sizes, int n_in,
                              void* d_out, int out_size, void* d_ws, size_t ws_size,
                              hipStream_t stream) {
    const float* x  = (const float*)d_in[0];
    const float* Wq = (const float*)d_in[1];
    const float* bq = (const float*)d_in[2];
    const float* Wk = (const float*)d_in[3];
    const float* bk = (const float*)d_in[4];
    const float* Wv = (const float*)d_in[5];
    const float* bv = (const float*)d_in[6];
    float* outp = (float*)d_out;

    ushort* ws = (ushort*)d_ws;
    const size_t XM = 4096 * 1024;
    const size_t WM = 1024 * 1024;
    ushort* xh = ws;                  // x hi -- dead after qkv_gemm
    ushort* xl = xh + XM;
    ushort* wh = xl + XM;             // W hi (3 x WM)
    ushort* wl = wh + 3 * WM;         // W lo (3 x WM)
    ushort* qh = wl + 3 * WM;         // Q hi  [32][2048][64]
    ushort* ql = qh + XM;             // Q lo
    ushort* kh = ql + XM;             // K hi
    ushort* kl = kh + XM;             // K lo
    ushort* vv = kl + XM;             // V   [bh][s][d]
    ushort* vt = xh;                  // V^T [bh][d][s] -- aliases xh (stream-ordered)

    cvt_split<<<2048, 256, 0, stream>>>(x, xh, xl, (int)(XM / 8));
    cvt_split<<<512, 256, 0, stream>>>(Wq, wh, wl, (int)(WM / 8));
    cvt_split<<<512, 256, 0, stream>>>(Wk, wh + WM, wl + WM, (int)(WM / 8));
    cvt_split<<<512, 256, 0, stream>>>(Wv, wh + 2 * WM, wl + 2 * WM, (int)(WM / 8));

    qkv_gemm<<<dim3(32, 8, 3), 256, 0, stream>>>(xh, xl, wh, wl, bq, bk, bv,
                                                 qh, ql, kh, kl, vv);

    transpose_v<<<dim3(32, 32), 256, 0, stream>>>(vv, vt);

    attn_fwd<<<dim3(32, 32), 256, 0, stream>>>(qh, ql, kh, kl, vt, outp);
}